// Round 8
// baseline (89.513 us; speedup 1.0000x reference)
//
#include <hip/hip_runtime.h>
#include <hip/hip_bf16.h>

#define BB 8
#define TT 512
#define DD 64
#define S_SCALE 1.2011224087864498f   // sqrt(log2(e)); exp(-u^2) = exp2(-(S*u)^2)

typedef float v2f __attribute__((ext_vector_type(2)));
typedef unsigned short ushort_t;

static __device__ __forceinline__ float fast_exp2(float v) {
#if __has_builtin(__builtin_amdgcn_exp2f)
    return __builtin_amdgcn_exp2f(v);
#else
    return exp2f(v);
#endif
}
static __device__ __forceinline__ float fast_rcp(float v) {
#if __has_builtin(__builtin_amdgcn_rcpf)
    return __builtin_amdgcn_rcpf(v);
#else
    return 1.0f / v;
#endif
}
static __device__ __forceinline__ v2f pk_fma(v2f a, v2f b, v2f c) {
#if __has_builtin(__builtin_elementwise_fma)
    return __builtin_elementwise_fma(a, b, c);
#else
    return a * b + c;
#endif
}
// dword holding 2 bf16 -> 2 f32 (lo element first: little-endian)
static __device__ __forceinline__ v2f lohi(unsigned u) {
    v2f r;
    r.x = __uint_as_float(u << 16);
    r.y = __uint_as_float(u & 0xffff0000u);
    return r;
}

// ------------- kernel 1: v = x@W^T + b ; bf16 copies of S*x and v -------------
__global__ __launch_bounds__(256) void rbf_pre(
    const float* __restrict__ x, const float* __restrict__ W,
    const float* __restrict__ bias, float* __restrict__ vv,
    __hip_bfloat16* __restrict__ xs16, __hip_bfloat16* __restrict__ vs16)
{
    const int t = threadIdx.x;
    const int w = t >> 6, l = t & 63;
    const int row = blockIdx.x * 4 + w;
    const float* xr = x + (size_t)row * DD;
    const float* wr = W + (size_t)l * DD;
    float acc = bias[l];
    #pragma unroll
    for (int d = 0; d < DD; d += 4) {
        float4 xv = *(const float4*)(xr + d);
        float4 wv = *(const float4*)(wr + d);
        acc = fmaf(xv.x, wv.x, acc); acc = fmaf(xv.y, wv.y, acc);
        acc = fmaf(xv.z, wv.z, acc); acc = fmaf(xv.w, wv.w, acc);
    }
    vv  [(size_t)row * DD + l] = acc;
    xs16[(size_t)row * DD + l] = __float2bfloat16(xr[l] * S_SCALE);
    vs16[(size_t)row * DD + l] = __float2bfloat16(acc);
}

// ------------- tile body: 4 i-rows x 64 j x 64 d, optional mirror -------------
// xrow0/vrow0 are WAVE-UNIFORM row pointers (scalar-load path). xls/vls are the
// bf16 j-tiles in LDS (row stride 72 -> 2-way bank alias = free). Per c-iter:
// exactly 2 dense ds_read_b128 serving 4 rows x 8 dims. diff uses raw x fused
// with the scale: u = S*xa - (S*xj)_bf16 via one pk_fma.
template <bool MIRROR>
static __device__ __forceinline__ void tile_compute(
    const float* __restrict__ xrow0, const float* __restrict__ vrow0,
    const ushort_t* xls, const ushort_t* vls,
    float* __restrict__ orow0, float* cbuf, int l, int ilocBase)
{
    v2f nr[4][2], nc[4][2], dn[4];
    #pragma unroll
    for (int r = 0; r < 4; ++r) {
        nr[r][0] = (v2f){0.f, 0.f}; nr[r][1] = (v2f){0.f, 0.f};
        nc[r][0] = (v2f){0.f, 0.f}; nc[r][1] = (v2f){0.f, 0.f};
        dn[r]    = (v2f){0.f, 0.f};
    }
    const v2f Sv = {S_SCALE, S_SCALE};

    #pragma unroll
    for (int c = 0; c < 8; ++c) {
        uint4 xjw = *(const uint4*)(xls + l * 72 + c * 8);
        uint4 vjw = *(const uint4*)(vls + l * 72 + c * 8);
        v2f xj0 = lohi(xjw.x), xj1 = lohi(xjw.y), xj2 = lohi(xjw.z), xj3 = lohi(xjw.w);
        v2f vj0 = lohi(vjw.x), vj1 = lohi(vjw.y), vj2 = lohi(vjw.z), vj3 = lohi(vjw.w);
        #pragma unroll
        for (int r = 0; r < 4; ++r) {
            float4 a0 = *(const float4*)(xrow0 + r * DD + c * 8);
            float4 a1 = *(const float4*)(xrow0 + r * DD + c * 8 + 4);
            float4 b0 = *(const float4*)(vrow0 + r * DD + c * 8);
            float4 b1 = *(const float4*)(vrow0 + r * DD + c * 8 + 4);
            v2f u0 = pk_fma((v2f){a0.x, a0.y}, Sv, -xj0);
            v2f u1 = pk_fma((v2f){a0.z, a0.w}, Sv, -xj1);
            v2f u2 = pk_fma((v2f){a1.x, a1.y}, Sv, -xj2);
            v2f u3 = pk_fma((v2f){a1.z, a1.w}, Sv, -xj3);
            u0 *= u0; u1 *= u1; u2 *= u2; u3 *= u3;
            v2f e0 = {fast_exp2(-u0.x), fast_exp2(-u0.y)};
            v2f e1 = {fast_exp2(-u1.x), fast_exp2(-u1.y)};
            v2f e2 = {fast_exp2(-u2.x), fast_exp2(-u2.y)};
            v2f e3 = {fast_exp2(-u3.x), fast_exp2(-u3.y)};
            nr[r][0] = pk_fma(e0, (v2f){b0.x, b0.y}, nr[r][0]);
            nr[r][0] = pk_fma(e1, (v2f){b0.z, b0.w}, nr[r][0]);
            nr[r][1] = pk_fma(e2, (v2f){b1.x, b1.y}, nr[r][1]);
            nr[r][1] = pk_fma(e3, (v2f){b1.z, b1.w}, nr[r][1]);
            if (MIRROR) {
                nc[r][0] = pk_fma(e0, vj0, nc[r][0]);
                nc[r][0] = pk_fma(e1, vj1, nc[r][0]);
                nc[r][1] = pk_fma(e2, vj2, nc[r][1]);
                nc[r][1] = pk_fma(e3, vj3, nc[r][1]);
            }
            dn[r] += (e0 + e1) + (e2 + e3);
        }
    }

    #pragma unroll
    for (int r = 0; r < 4; ++r) {
        float rd = fast_rcp(dn[r].x + dn[r].y);
        v2f sr = nr[r][0] + nr[r][1];
        orow0[(size_t)r * TT + l] = (sr.x + sr.y) * rd;   // coalesced 256 B
        if (MIRROR) {
            v2f sc = nc[r][0] + nc[r][1];
            cbuf[l * 20 + ilocBase + r] = (sc.x + sc.y) * rd;
        }
    }
}

// ------------- kernel 2: symmetric pairwise tiles (16 i x 64 j) -------------
// R5-validated mapping: 144 tiles/batch; idx<32 = diagonal band (no mirror),
// else triangle walk (mirror). Block = 256 thr / 4 waves; wave w owns rows
// i0 + 4w .. +4. Mirror stashed in cbuf, flushed as 64-B aligned float4.
__global__ __launch_bounds__(256, 4) void rbf_sym(
    const float* __restrict__ x, const float* __restrict__ vv,
    const __hip_bfloat16* __restrict__ xs16, const __hip_bfloat16* __restrict__ vs16,
    float* __restrict__ out)
{
    const int bid = blockIdx.x;
    const int b = bid / 144;
    int idx = bid - b * 144;
    int st, jt, isA;
    if (idx < 32) { jt = idx >> 2; st = 4 * jt + (idx & 3); isA = 0; }
    else {
        int k = idx - 32, tt = 1;
        while (k >= 4 * tt) { k -= 4 * tt; ++tt; }
        jt = tt; st = k; isA = 1;
    }
    const int i0 = st * 16, j0 = jt * 64;

    const int tid = threadIdx.x;
    const int w = tid >> 6, l = tid & 63;
    const int wau = __builtin_amdgcn_readfirstlane(w);   // force scalar path

    __shared__ ushort_t xls[64 * 72];   // bf16 S*xj tile, stride 72 (144 B rows)
    __shared__ ushort_t vls[64 * 72];   // bf16 vj tile
    __shared__ float    cbuf[64 * 20];  // mirror [j][iloc 0..15], stride 20

    // ---- stage j-tile: 2 x 8 KB contiguous bf16, fully coalesced ----
    {
        const uint4* xsrc = (const uint4*)(xs16 + ((size_t)b * TT + j0) * DD);
        const uint4* vsrc = (const uint4*)(vs16 + ((size_t)b * TT + j0) * DD);
        #pragma unroll
        for (int u = 0; u < 2; ++u) {
            int g = u * 256 + tid;          // 512 uint4 granules per array
            int r = g >> 3, c8 = g & 7;
            *(uint4*)(xls + r * 72 + c8 * 8) = xsrc[g];
            *(uint4*)(vls + r * 72 + c8 * 8) = vsrc[g];
        }
    }
    __syncthreads();

    const int ib = b * TT + i0 + wau * 4;                // wave-uniform
    const float* xrow0 = x  + (size_t)ib * DD;
    const float* vrow0 = vv + (size_t)ib * DD;
    float* outb  = out + (size_t)b * TT * TT;
    float* orow0 = outb + (size_t)(i0 + wau * 4) * TT + j0;

    if (isA) tile_compute<true >(xrow0, vrow0, xls, vls, orow0, cbuf, l, wau * 4);
    else     tile_compute<false>(xrow0, vrow0, xls, vls, orow0, cbuf, l, wau * 4);

    __syncthreads();
    if (isA) {
        // flush mirror: out[j0+j][i0 .. i0+16), 64-B aligned float4 per thread
        int j = tid >> 2, qf = (tid & 3) * 4;
        float4 cv = *(const float4*)(cbuf + j * 20 + qf);
        *(float4*)(outb + (size_t)(j0 + j) * TT + i0 + qf) = cv;
    }
}

extern "C" void kernel_launch(void* const* d_in, const int* in_sizes, int n_in,
                              void* d_out, int out_size, void* d_ws, size_t ws_size,
                              hipStream_t stream) {
    const float* x    = (const float*)d_in[0];
    const float* W    = (const float*)d_in[1];
    const float* bias = (const float*)d_in[2];
    float* out        = (float*)d_out;

    float* vv             = (float*)d_ws;                                  // 1 MB
    __hip_bfloat16* xs16  = (__hip_bfloat16*)((char*)d_ws + (1 << 20));    // 0.5 MB
    __hip_bfloat16* vs16  = (__hip_bfloat16*)((char*)d_ws + (3 << 19));    // 0.5 MB

    rbf_pre<<<BB * TT / 4, 256, 0, stream>>>(x, W, bias, vv, xs16, vs16);
    rbf_sym<<<BB * 144, 256, 0, stream>>>(x, vv, xs16, vs16, out);
}

// Round 9
// 88.667 us; speedup vs baseline: 1.0095x; 1.0095x over previous
//
#include <hip/hip_runtime.h>

#define BB 8
#define TT 512
#define DD 64
#define S_SCALE 1.2011224087864498f   // sqrt(log2(e)); exp(-u^2) = exp2(-(S*u)^2)

typedef float v2f __attribute__((ext_vector_type(2)));
typedef float f8  __attribute__((ext_vector_type(8)));
typedef _Float16 h8 __attribute__((ext_vector_type(8)));

static __device__ __forceinline__ float fast_exp2(float v) {
#if __has_builtin(__builtin_amdgcn_exp2f)
    return __builtin_amdgcn_exp2f(v);
#else
    return exp2f(v);
#endif
}
static __device__ __forceinline__ float fast_rcp(float v) {
#if __has_builtin(__builtin_amdgcn_rcpf)
    return __builtin_amdgcn_rcpf(v);
#else
    return 1.0f / v;
#endif
}
static __device__ __forceinline__ v2f pk_fma(v2f a, v2f b, v2f c) {
#if __has_builtin(__builtin_elementwise_fma)
    return __builtin_elementwise_fma(a, b, c);
#else
    return a * b + c;
#endif
}

// ------------- kernel 1: v = x@W^T + b ; f16 copies of S*x and v -------------
__global__ __launch_bounds__(256) void rbf_pre(
    const float* __restrict__ x, const float* __restrict__ W,
    const float* __restrict__ bias,
    _Float16* __restrict__ xh, _Float16* __restrict__ vh)
{
    const int t = threadIdx.x;
    const int w = t >> 6, l = t & 63;
    const int row = blockIdx.x * 4 + w;
    const float* xr = x + (size_t)row * DD;
    const float* wr = W + (size_t)l * DD;
    float acc = bias[l];
    #pragma unroll
    for (int d = 0; d < DD; d += 4) {
        float4 xv = *(const float4*)(xr + d);
        float4 wv = *(const float4*)(wr + d);
        acc = fmaf(xv.x, wv.x, acc); acc = fmaf(xv.y, wv.y, acc);
        acc = fmaf(xv.z, wv.z, acc); acc = fmaf(xv.w, wv.w, acc);
    }
    xh[(size_t)row * DD + l] = (_Float16)(xr[l] * S_SCALE);
    vh[(size_t)row * DD + l] = (_Float16)acc;
}

// ------------- tile body: 4 i-rows x 64 j x 64 d, optional mirror -------------
// All operands f16 in LDS. Per c-iter (8 dims): 2 dense ds_read_b128 (lane's
// xj/vj) + per r-row 2 broadcast ds_read_b128 (xi/vi). cvt to f32, packed
// v2f math, exp2 with neg input modifier. Accumulators in-lane (no reductions).
template <bool MIRROR>
static __device__ __forceinline__ void tile_compute(
    const _Float16* xls, const _Float16* vls,
    const _Float16* xis, const _Float16* vis,
    float* __restrict__ orow0, float* cbuf, int l, int wau)
{
    v2f nr[4][2], nc[4][2], dn[4];
    #pragma unroll
    for (int r = 0; r < 4; ++r) {
        nr[r][0] = (v2f){0.f, 0.f}; nr[r][1] = (v2f){0.f, 0.f};
        nc[r][0] = (v2f){0.f, 0.f}; nc[r][1] = (v2f){0.f, 0.f};
        dn[r]    = (v2f){0.f, 0.f};
    }

    #pragma unroll
    for (int c = 0; c < 8; ++c) {
        h8 xjh = *(const h8*)(xls + l * 72 + c * 8);    // ds_read_b128 dense
        h8 vjh = *(const h8*)(vls + l * 72 + c * 8);
        f8 xj = __builtin_convertvector(xjh, f8);
        f8 vj = __builtin_convertvector(vjh, f8);
        const v2f* xj2 = (const v2f*)&xj;
        const v2f* vj2 = (const v2f*)&vj;
        #pragma unroll
        for (int r = 0; r < 4; ++r) {
            h8 xih = *(const h8*)(xis + (wau * 4 + r) * 72 + c * 8); // broadcast
            h8 vih = *(const h8*)(vis + (wau * 4 + r) * 72 + c * 8); // broadcast
            f8 xi = __builtin_convertvector(xih, f8);
            f8 vi = __builtin_convertvector(vih, f8);
            const v2f* xi2 = (const v2f*)&xi;
            const v2f* vi2 = (const v2f*)&vi;
            #pragma unroll
            for (int q = 0; q < 4; ++q) {
                v2f u = xi2[q] - xj2[q];
                u *= u;
                v2f e = {fast_exp2(-u.x), fast_exp2(-u.y)};
                nr[r][q & 1] = pk_fma(e, vi2[q], nr[r][q & 1]);
                if (MIRROR) nc[r][q & 1] = pk_fma(e, vj2[q], nc[r][q & 1]);
                dn[r] += e;
            }
        }
    }

    #pragma unroll
    for (int r = 0; r < 4; ++r) {
        float rd = fast_rcp(dn[r].x + dn[r].y);
        v2f sr = nr[r][0] + nr[r][1];
        orow0[(size_t)r * TT + l] = (sr.x + sr.y) * rd;   // coalesced 256 B
        if (MIRROR) {
            v2f sc = nc[r][0] + nc[r][1];
            cbuf[l * 20 + wau * 4 + r] = (sc.x + sc.y) * rd;
        }
    }
}

// ------------- kernel 2: symmetric pairwise tiles (16 i x 64 j) -------------
// R8-validated mapping: 144 tiles/batch; idx<32 = diagonal band (no mirror),
// else triangle walk (mirror -> writes out[j,i] chunk too).
__global__ __launch_bounds__(256, 4) void rbf_sym(
    const _Float16* __restrict__ xh, const _Float16* __restrict__ vh,
    float* __restrict__ out)
{
    const int bid = blockIdx.x;
    const int b = bid / 144;
    int idx = bid - b * 144;
    int st, jt, isA;
    if (idx < 32) { jt = idx >> 2; st = 4 * jt + (idx & 3); isA = 0; }
    else {
        int k = idx - 32, tt = 1;
        while (k >= 4 * tt) { k -= 4 * tt; ++tt; }
        jt = tt; st = k; isA = 1;
    }
    const int i0 = st * 16, j0 = jt * 64;

    const int tid = threadIdx.x;
    const int w = tid >> 6, l = tid & 63;
    const int wau = __builtin_amdgcn_readfirstlane(w);

    __shared__ __align__(16) _Float16 xls[64 * 72];  // f16 S*xj tile, stride 72 (144 B rows)
    __shared__ __align__(16) _Float16 vls[64 * 72];  // f16 vj tile
    __shared__ __align__(16) _Float16 xis[16 * 72];  // f16 S*xi strip
    __shared__ __align__(16) _Float16 vis[16 * 72];  // f16 vi strip
    __shared__ float cbuf[64 * 20];                  // mirror [j][iloc], stride 20

    // ---- stage j-tiles: 8 KB each, fully coalesced uint4 ----
    {
        const uint4* xsrc = (const uint4*)(xh + ((size_t)b * TT + j0) * DD);
        const uint4* vsrc = (const uint4*)(vh + ((size_t)b * TT + j0) * DD);
        #pragma unroll
        for (int u = 0; u < 2; ++u) {
            int g = u * 256 + tid;          // 512 uint4 granules per array
            int r = g >> 3, c = g & 7;
            *(uint4*)(xls + r * 72 + c * 8) = xsrc[g];
            *(uint4*)(vls + r * 72 + c * 8) = vsrc[g];
        }
        // ---- stage i-strip: 2 KB each; threads 0-127 -> xi, 128-255 -> vi ----
        const uint4* isrc = (tid < 128)
            ? (const uint4*)(xh + ((size_t)b * TT + i0) * DD)
            : (const uint4*)(vh + ((size_t)b * TT + i0) * DD);
        _Float16* idst = (tid < 128) ? xis : vis;
        int g = tid & 127;                  // 128 granules = 16 rows x 8
        int r = g >> 3, c = g & 7;
        *(uint4*)(idst + r * 72 + c * 8) = isrc[g];
    }
    __syncthreads();

    float* outb  = out + (size_t)b * TT * TT;
    float* orow0 = outb + (size_t)(i0 + wau * 4) * TT + j0;

    if (isA) tile_compute<true >(xls, vls, xis, vis, orow0, cbuf, l, wau);
    else     tile_compute<false>(xls, vls, xis, vis, orow0, cbuf, l, wau);

    __syncthreads();
    if (isA) {
        // flush mirror: out[j0+j][i0 .. i0+16), 64-B aligned float4 per thread
        int j = tid >> 2, qf = (tid & 3) * 4;
        float4 cv = *(const float4*)(cbuf + j * 20 + qf);
        *(float4*)(outb + (size_t)(j0 + j) * TT + i0 + qf) = cv;
    }
}

extern "C" void kernel_launch(void* const* d_in, const int* in_sizes, int n_in,
                              void* d_out, int out_size, void* d_ws, size_t ws_size,
                              hipStream_t stream) {
    const float* x    = (const float*)d_in[0];
    const float* W    = (const float*)d_in[1];
    const float* bias = (const float*)d_in[2];
    float* out        = (float*)d_out;

    _Float16* xh = (_Float16*)d_ws;                       // 0.5 MB
    _Float16* vh = (_Float16*)((char*)d_ws + (1 << 19));  // 0.5 MB

    rbf_pre<<<BB * TT / 4, 256, 0, stream>>>(x, W, bias, xh, vh);
    rbf_sym<<<BB * 144, 256, 0, stream>>>(xh, vh, out);
}

// Round 10
// 84.762 us; speedup vs baseline: 1.0561x; 1.0461x over previous
//
#include <hip/hip_runtime.h>

#define BB 8
#define TT 512
#define DD 64
#define S_SCALE 1.2011224087864498f   // sqrt(log2(e)); exp(-u^2) = exp2(-(S*u)^2)

typedef float v2f __attribute__((ext_vector_type(2)));
typedef float f8  __attribute__((ext_vector_type(8)));
typedef _Float16 h8 __attribute__((ext_vector_type(8)));

static __device__ __forceinline__ float fast_exp2(float v) {
#if __has_builtin(__builtin_amdgcn_exp2f)
    return __builtin_amdgcn_exp2f(v);
#else
    return exp2f(v);
#endif
}
static __device__ __forceinline__ float fast_rcp(float v) {
#if __has_builtin(__builtin_amdgcn_rcpf)
    return __builtin_amdgcn_rcpf(v);
#else
    return 1.0f / v;
#endif
}
static __device__ __forceinline__ v2f pk_fma(v2f a, v2f b, v2f c) {
#if __has_builtin(__builtin_elementwise_fma)
    return __builtin_elementwise_fma(a, b, c);
#else
    return a * b + c;
#endif
}

// ------- kernel 1: v = x@W^T + b ; f16 S*x, f16 v, f32 v -------
__global__ __launch_bounds__(256) void rbf_pre(
    const float* __restrict__ x, const float* __restrict__ W,
    const float* __restrict__ bias,
    _Float16* __restrict__ xh, _Float16* __restrict__ vh,
    float* __restrict__ vv)
{
    const int t = threadIdx.x;
    const int w = t >> 6, l = t & 63;
    const int row = blockIdx.x * 4 + w;
    const float* xr = x + (size_t)row * DD;
    const float* wr = W + (size_t)l * DD;
    float acc = bias[l];
    #pragma unroll
    for (int d = 0; d < DD; d += 4) {
        float4 xv = *(const float4*)(xr + d);
        float4 wv = *(const float4*)(wr + d);
        acc = fmaf(xv.x, wv.x, acc); acc = fmaf(xv.y, wv.y, acc);
        acc = fmaf(xv.z, wv.z, acc); acc = fmaf(xv.w, wv.w, acc);
    }
    xh[(size_t)row * DD + l] = (_Float16)(xr[l] * S_SCALE);
    vh[(size_t)row * DD + l] = (_Float16)acc;
    vv[(size_t)row * DD + l] = acc;
}

// ------- tile body: 2 i-rows (per wave) x 64 j x 64 d, optional mirror -------
template <bool MIRROR>
static __device__ __forceinline__ void tile_compute(
    const _Float16* xls, const _Float16* vls,
    const float* xis, const float* vis,
    float* __restrict__ orow0, float* cbuf, int l, int wau)
{
    v2f nr[2][2], nc[2][2], dn[2];
    #pragma unroll
    for (int r = 0; r < 2; ++r) {
        nr[r][0] = (v2f){0.f, 0.f}; nr[r][1] = (v2f){0.f, 0.f};
        nc[r][0] = (v2f){0.f, 0.f}; nc[r][1] = (v2f){0.f, 0.f};
        dn[r]    = (v2f){0.f, 0.f};
    }

    #pragma unroll
    for (int c = 0; c < 8; ++c) {
        h8 xjh = *(const h8*)(xls + l * 72 + c * 8);   // dense ds_read_b128
        h8 vjh = *(const h8*)(vls + l * 72 + c * 8);
        f8 xj = __builtin_convertvector(xjh, f8);
        f8 vj = __builtin_convertvector(vjh, f8);
        const v2f* xj2 = (const v2f*)&xj;
        const v2f* vj2 = (const v2f*)&vj;
        #pragma unroll
        for (int r = 0; r < 2; ++r) {
            const v2f* xi2 = (const v2f*)(xis + (wau * 2 + r) * DD + c * 8); // bcast
            const v2f* vi2 = (const v2f*)(vis + (wau * 2 + r) * DD + c * 8); // bcast
            #pragma unroll
            for (int q = 0; q < 4; ++q) {
                v2f u = xi2[q] - xj2[q];
                u *= u;
                v2f e = {fast_exp2(-u.x), fast_exp2(-u.y)};
                nr[r][q & 1] = pk_fma(e, vi2[q], nr[r][q & 1]);
                if (MIRROR) nc[r][q & 1] = pk_fma(e, vj2[q], nc[r][q & 1]);
                dn[r] += e;
            }
        }
    }

    #pragma unroll
    for (int r = 0; r < 2; ++r) {
        float rd = fast_rcp(dn[r].x + dn[r].y);
        v2f sr = nr[r][0] + nr[r][1];
        orow0[(size_t)r * TT + l] = (sr.x + sr.y) * rd;   // coalesced 256 B
        if (MIRROR) {
            v2f sc = nc[r][0] + nc[r][1];
            cbuf[l * 12 + wau * 2 + r] = (sc.x + sc.y) * rd;
        }
    }
}

// ------- kernel 2: symmetric pairwise tiles, 8 i x 64 j, 288/batch -------
// idx<64: diagonal band (ti = 8jt + r, no mirror); else triangle walk
// (ti < 8jt, mirror writes out[j, i0..i0+8) too). Grid 2304 -> 9 blocks/CU
// of work, ~6-7 resident (LDS ~23.3 KB) = 24-28 waves/CU.
__global__ __launch_bounds__(256, 6) void rbf_sym(
    const float* __restrict__ x,
    const _Float16* __restrict__ xh, const _Float16* __restrict__ vh,
    const float* __restrict__ vv, float* __restrict__ out)
{
    const int bid = blockIdx.x;
    const int b = bid / 288;
    int idx = bid - b * 288;
    int ti, jt, isA;
    if (idx < 64) { jt = idx >> 3; ti = 8 * jt + (idx & 7); isA = 0; }
    else {
        int k = idx - 64, t = 1;
        while (k >= 8 * t) { k -= 8 * t; ++t; }   // <=7 scalar iters
        jt = t; ti = k; isA = 1;
    }
    const int i0 = ti * 8, j0 = jt * 64;

    const int tid = threadIdx.x;
    const int w = tid >> 6, l = tid & 63;
    const int wau = __builtin_amdgcn_readfirstlane(w);

    __shared__ __align__(16) _Float16 xls[64 * 72];  // f16 S*xj tile (144 B rows)
    __shared__ __align__(16) _Float16 vls[64 * 72];  // f16 vj tile
    __shared__ __align__(16) float xis[8 * DD];      // f32 S*xi strip (bcast reads)
    __shared__ __align__(16) float vis[8 * DD];      // f32 vi strip
    __shared__ float cbuf[64 * 12];                  // mirror [j][iloc 0..7]

    // ---- stage j-tiles: 8 KB each, coalesced uint4 ----
    {
        const uint4* xsrc = (const uint4*)(xh + ((size_t)b * TT + j0) * DD);
        const uint4* vsrc = (const uint4*)(vh + ((size_t)b * TT + j0) * DD);
        #pragma unroll
        for (int u = 0; u < 2; ++u) {
            int g = u * 256 + tid;          // 512 uint4 granules per array
            int r = g >> 3, c = g & 7;
            *(uint4*)(xls + r * 72 + c * 8) = xsrc[g];
            *(uint4*)(vls + r * 72 + c * 8) = vsrc[g];
        }
        // ---- stage i-strips: 2 KB each; tid<128 -> S*x (f32), else -> v (f32)
        int g = tid & 127;                  // 128 f4 granules = 8 rows x 16
        int r = g >> 4, c4 = (g & 15) * 4;
        if (tid < 128) {
            float4 v = *(const float4*)(x + ((size_t)(b * TT + i0 + r)) * DD + c4);
            v.x *= S_SCALE; v.y *= S_SCALE; v.z *= S_SCALE; v.w *= S_SCALE;
            *(float4*)(xis + r * DD + c4) = v;
        } else {
            *(float4*)(vis + r * DD + c4) =
                *(const float4*)(vv + ((size_t)(b * TT + i0 + r)) * DD + c4);
        }
    }
    __syncthreads();

    float* outb  = out + (size_t)b * TT * TT;
    float* orow0 = outb + (size_t)(i0 + wau * 2) * TT + j0;

    if (isA) tile_compute<true >(xls, vls, xis, vis, orow0, cbuf, l, wau);
    else     tile_compute<false>(xls, vls, xis, vis, orow0, cbuf, l, wau);

    __syncthreads();
    if (isA && tid < 128) {
        // flush mirror: out[j0+j][i0 .. i0+8), 16-B aligned float4 per thread
        int j = tid >> 1, qf = (tid & 1) * 4;
        float4 cv = *(const float4*)(cbuf + j * 12 + qf);
        *(float4*)(outb + (size_t)(j0 + j) * TT + i0 + qf) = cv;
    }
}

extern "C" void kernel_launch(void* const* d_in, const int* in_sizes, int n_in,
                              void* d_out, int out_size, void* d_ws, size_t ws_size,
                              hipStream_t stream) {
    const float* x    = (const float*)d_in[0];
    const float* W    = (const float*)d_in[1];
    const float* bias = (const float*)d_in[2];
    float* out        = (float*)d_out;

    _Float16* xh = (_Float16*)d_ws;                       // 0.5 MB
    _Float16* vh = (_Float16*)((char*)d_ws + (1 << 19));  // 0.5 MB
    float*    vv = (float*)((char*)d_ws + (1 << 20));     // 1 MB

    rbf_pre<<<BB * TT / 4, 256, 0, stream>>>(x, W, bias, xh, vh, vv);
    rbf_sym<<<BB * 288, 256, 0, stream>>>(x, xh, vh, vv, out);
}